// Round 3
// baseline (348.013 us; speedup 1.0000x reference)
//
#include <hip/hip_runtime.h>
#include <hip/hip_bf16.h>

typedef __attribute__((ext_vector_type(8))) short bf16x8;
typedef __attribute__((ext_vector_type(4))) short bf16x4;
typedef __attribute__((ext_vector_type(4))) float f32x4;

// ws layout (bytes):
//   WTf  [36 ct][6 ks][64 ln][8] bf16 @ 0       (221184 B)  fragment-major [Wq|Wk|Wv]
//   WfcTf[12 ct][6 ks][64 ln][8] bf16 @ 221184  (73728 B)
//   biasT[3][49 k][49 q] f32        @ 294912    (28812 B)   0=plain 1=+LOWER 2=+RIGHT

__device__ __forceinline__ short f2bf(float f) {
  unsigned u = __float_as_uint(f);
  unsigned r = (u + 0x7FFFu + ((u >> 16) & 1u)) >> 16;
  return (short)(unsigned short)r;
}
// LDS anti-bank-conflict swizzle on flat short index: byte bits[6:4] ^= byte bits[9:7].
// Stays within each 64-short chunk; preserves 8-short (16B) block contiguity.
__device__ __forceinline__ int swz(int f) { return f ^ (((f >> 6) & 7) << 3); }

__global__ void prep_kernel(const float* __restrict__ Wq, const float* __restrict__ Wk,
                            const float* __restrict__ Wv, const float* __restrict__ Wfc,
                            const float* __restrict__ pos,
                            short* __restrict__ WTf, short* __restrict__ WfcTf,
                            float* __restrict__ biasT) {
  int i0 = blockIdx.x * blockDim.x + threadIdx.x;
  int stride = gridDim.x * blockDim.x;
  // WTf fragment-major: lane ln reads 8 bf16 at [ct][ks][ln]: col=ct*16+(ln&15),
  // k = ks*32 + (ln>>4)*8 + e
  for (int o = i0; o < 110592; o += stride) {
    int e = o & 7, ln = (o >> 3) & 63, t = o >> 9;
    int ks = t % 6, ct = t / 6;
    int col = ct * 16 + (ln & 15);
    int k = ks * 32 + ((ln >> 4) << 3) + e;
    const float* W = (col < 192) ? Wq : (col < 384) ? Wk : Wv;
    WTf[o] = f2bf(W[k * 192 + (col % 192)]);
  }
  for (int o = i0; o < 36864; o += stride) {
    int e = o & 7, ln = (o >> 3) & 63, t = o >> 9;
    int ks = t % 6, ct = t / 6;
    int col = ct * 16 + (ln & 15);
    int k = ks * 32 + ((ln >> 4) << 3) + e;
    WfcTf[o] = f2bf(Wfc[k * 192 + col]);
  }
  // transposed bias: biasT[t][k*49 + q] = bias(q,k)  (masks are symmetric in q,k)
  for (int idx = i0; idx < 3 * 2401; idx += stride) {
    int t = idx / 2401, r = idx - t * 2401;
    int kk = r / 49, q = r - kk * 49;
    int ri = kk / 7 - q / 7 + 6;
    int rj = kk % 7 - q % 7 + 6;
    float v = pos[ri * 13 + rj];
    if (t == 1 && ((q >= 28) != (kk >= 28))) v = -1e30f;
    if (t == 2 && ((q % 7 >= 4) != (kk % 7 >= 4))) v = -1e30f;
    biasT[idx] = v;
  }
}

__launch_bounds__(384, 2)
__global__ void swin_fused(const float* __restrict__ x,
                           const short* __restrict__ WTf,
                           const short* __restrict__ WfcTf,
                           const float* __restrict__ biasT,
                           const float* __restrict__ bfc,
                           float* __restrict__ out) {
  // LDS: (9408 + 9408 + 12288) * 2 = 62208 B  -> 2 blocks/CU
  __shared__ short qf[9408];      // q[49][192] flat (swizzled); reused for attn-out
  __shared__ short kf[9408];      // k[49][192] flat (swizzled)
  __shared__ short vT[12288];     // per-window v^T: [6][32 d][64 tok] (swizzled), tok-padded 0

  const int bid = blockIdx.x;
  const int b = bid >> 6;
  const int g = bid & 63;
  const int tid = threadIdx.x;
  const int wave = tid >> 6;
  const int lane = tid & 63;
  const int lrow = lane & 15;            // within-tile row/col
  const int lk8 = (lane >> 4) << 3;      // k-chunk base {0,8,16,24}
  const int lg4 = (lane >> 4) << 2;      // D-frag row base {0,4,8,12}

  const bf16x8 z8 = {0, 0, 0, 0, 0, 0, 0, 0};
  const f32x4 z4 = {0.f, 0.f, 0.f, 0.f};

  for (int i = tid; i < 12288; i += 384) vT[i] = 0;   // zero pad (swizzle-safe: full clear)
  __syncthreads();

  // per-mt x row pointers (roll applied); low register cost, computed once
  const float* xrow[4];
  bool rok[4];
  #pragma unroll
  for (int mt = 0; mt < 4; ++mt) {
    int row = mt * 16 + lrow;
    rok[mt] = (row < 49);
    int t = g * 49 + (row < 49 ? row : 0);
    int h = t / 56, w = t - h * 56;
    int hs = h + 3; if (hs >= 56) hs -= 56;        // roll(-3)
    int ws2 = w + 3; if (ws2 >= 56) ws2 -= 56;
    xrow[mt] = x + ((b * 56 + hs) * 56 + ws2) * 192 + lk8;
  }

  // ---------------- Phase 1: QKV = x_shifted(49 tok) @ [Wq|Wk|Wv]  (M=64pad,N=576,K=192)
  // accumulator-major, two N-halves of 3 tiles each: acc[4][3] = 48 VGPRs live.
  #pragma unroll 1
  for (int half = 0; half < 2; ++half) {
    f32x4 acc[4][3];
    #pragma unroll
    for (int mt = 0; mt < 4; ++mt)
      #pragma unroll
      for (int n3 = 0; n3 < 3; ++n3) acc[mt][n3] = z4;

    #pragma unroll
    for (int ks = 0; ks < 6; ++ks) {
      bf16x8 afrag[4];
      #pragma unroll
      for (int mt = 0; mt < 4; ++mt) {
        if (rok[mt]) {
          const float* p = xrow[mt] + 32 * ks;
          float4 f0 = *(const float4*)(p);
          float4 f1 = *(const float4*)(p + 4);
          bf16x8 a;
          a[0] = f2bf(f0.x); a[1] = f2bf(f0.y); a[2] = f2bf(f0.z); a[3] = f2bf(f0.w);
          a[4] = f2bf(f1.x); a[5] = f2bf(f1.y); a[6] = f2bf(f1.z); a[7] = f2bf(f1.w);
          afrag[mt] = a;
        } else {
          afrag[mt] = z8;
        }
      }
      #pragma unroll
      for (int n3 = 0; n3 < 3; ++n3) {
        int nt = half * 3 + n3;
        bf16x8 bfrag = *(const bf16x8*)(WTf + ((wave * 6 + nt) * 6 + ks) * 512 + (lane << 3));
        #pragma unroll
        for (int mt = 0; mt < 4; ++mt)
          acc[mt][n3] = __builtin_amdgcn_mfma_f32_16x16x32_bf16(afrag[mt], bfrag, acc[mt][n3], 0, 0, 0);
      }
    }
    // epilogue for this half
    #pragma unroll
    for (int n3 = 0; n3 < 3; ++n3) {
      int col = wave * 96 + (half * 3 + n3) * 16 + lrow;   // 0..575
      #pragma unroll
      for (int mt = 0; mt < 4; ++mt) {
        #pragma unroll
        for (int jj = 0; jj < 4; ++jj) {
          int rowD = mt * 16 + lg4 + jj;
          if (rowD < 49) {
            short v = f2bf(acc[mt][n3][jj]);
            if (col < 192) {
              qf[swz(rowD * 192 + col)] = v;
            } else if (col < 384) {
              kf[swz(rowD * 192 + col - 192)] = v;
            } else {
              int flat = rowD * 192 + col - 384;       // position in [49][192] v-flat
              int win2 = flat / 1568;
              int rem = flat - win2 * 1568;
              vT[swz((win2 * 32 + (rem & 31)) * 64 + (rem >> 5))] = v;
            }
          }
        }
      }
    }
  }
  __syncthreads();

  // ---------------- Phase 2: attention, wave j owns window j. Swapped QK^T:
  // S^T = mfma(K, Q) so lane regs hold P^T in the B-layout of a K=16 MFMA.
  const int j = wave;
  const int qbase = j * 1568;
  {
    bf16x8 ka[4], qb[4];
    #pragma unroll
    for (int t = 0; t < 4; ++t) {
      int row = t * 16 + lrow;
      ka[t] = (row < 49) ? *(const bf16x8*)(kf + swz(qbase + row * 32 + lk8)) : z8;
      qb[t] = (row < 49) ? *(const bf16x8*)(qf + swz(qbase + row * 32 + lk8)) : z8;
    }
    f32x4 st[4][4];   // st[kt][qt]: S^T[k = kt*16+lg4+jj][q = qt*16+lrow]
    #pragma unroll
    for (int kt = 0; kt < 4; ++kt)
      #pragma unroll
      for (int qt = 0; qt < 4; ++qt)
        st[kt][qt] = __builtin_amdgcn_mfma_f32_16x16x32_bf16(ka[kt], qb[qt], z4, 0, 0, 0);

    int win = (g * 6 + j) & 63;
    const float* bt = biasT + ((win >= 56) ? 2401 : (win == 7) ? 4802 : 0);
    #pragma unroll
    for (int kt = 0; kt < 4; ++kt)
      #pragma unroll
      for (int jj = 0; jj < 4; ++jj) {
        int kk = kt * 16 + lg4 + jj;
        #pragma unroll
        for (int qt = 0; qt < 4; ++qt) {
          int qq = qt * 16 + lrow;
          st[kt][qt][jj] = (kk < 49 && qq < 49)
              ? st[kt][qt][jj] * 5.65685424949238f + bt[kk * 49 + qq]   // *sqrt(32)
              : -1e30f;
        }
      }

    // register softmax over k for each q-column, + pack P^T to bf16 B-frags
    bf16x4 pb[4][4];
    #pragma unroll
    for (int qt = 0; qt < 4; ++qt) {
      float m = -1e30f;
      #pragma unroll
      for (int kt = 0; kt < 4; ++kt)
        #pragma unroll
        for (int jj = 0; jj < 4; ++jj)
          m = fmaxf(m, st[kt][qt][jj]);
      m = fmaxf(m, __shfl_xor(m, 16));
      m = fmaxf(m, __shfl_xor(m, 32));
      float sum = 0.f;
      #pragma unroll
      for (int kt = 0; kt < 4; ++kt)
        #pragma unroll
        for (int jj = 0; jj < 4; ++jj) {
          float e = __expf(st[kt][qt][jj] - m);
          st[kt][qt][jj] = e;
          sum += e;
        }
      sum += __shfl_xor(sum, 16);
      sum += __shfl_xor(sum, 32);
      float inv = 1.0f / sum;
      #pragma unroll
      for (int kt = 0; kt < 4; ++kt) {
        bf16x4 p = {f2bf(st[kt][qt][0] * inv), f2bf(st[kt][qt][1] * inv),
                    f2bf(st[kt][qt][2] * inv), f2bf(st[kt][qt][3] * inv)};
        pb[kt][qt] = p;
      }
    }

    // PV: O^T[d][q] = sum_k V^T[d][k] * P^T[k][q], 4 k-tiles of 16
    f32x4 o[2][4] = {{z4, z4, z4, z4}, {z4, z4, z4, z4}};
    #pragma unroll
    for (int dt = 0; dt < 2; ++dt)
      #pragma unroll
      for (int kt = 0; kt < 4; ++kt) {
        bf16x4 va = *(const bf16x4*)(vT + swz((j * 32 + dt * 16 + lrow) * 64 + kt * 16 + lg4));
#if __has_builtin(__builtin_amdgcn_mfma_f32_16x16x16bf16_1k)
        #pragma unroll
        for (int qt = 0; qt < 4; ++qt)
          o[dt][qt] = __builtin_amdgcn_mfma_f32_16x16x16bf16_1k(va, pb[kt][qt], o[dt][qt], 0, 0, 0);
#else
        // padded K=32 fallback: both operands put the 4 real k-values at e=0..3 of each chunk
        bf16x8 va8 = {va[0], va[1], va[2], va[3], 0, 0, 0, 0};
        #pragma unroll
        for (int qt = 0; qt < 4; ++qt) {
          bf16x8 pb8 = {pb[kt][qt][0], pb[kt][qt][1], pb[kt][qt][2], pb[kt][qt][3], 0, 0, 0, 0};
          o[dt][qt] = __builtin_amdgcn_mfma_f32_16x16x32_bf16(va8, pb8, o[dt][qt], 0, 0, 0);
        }
#endif
      }

    // attn-out overwrites q region (same flat positions). Safe: qb consumed via reg deps.
    #pragma unroll
    for (int qt = 0; qt < 4; ++qt) {
      int qq = qt * 16 + lrow;
      if (qq < 49) {
        #pragma unroll
        for (int dt = 0; dt < 2; ++dt)
          #pragma unroll
          for (int jj = 0; jj < 4; ++jj) {
            int d = dt * 16 + lg4 + jj;
            qf[swz(qbase + qq * 32 + d)] = f2bf(o[dt][qt][jj]);
          }
      }
    }
  }
  __syncthreads();

  // ---------------- Phase 3: out = attnout[49][192] @ Wfc + bfc, inverse roll
  // oa loaded per-ks inside the loop; acc[4][2] = 32 VGPRs live.
  {
    f32x4 acc[4][2];
    #pragma unroll
    for (int mt = 0; mt < 4; ++mt)
      #pragma unroll
      for (int nt = 0; nt < 2; ++nt) acc[mt][nt] = z4;

    #pragma unroll
    for (int ks = 0; ks < 6; ++ks) {
      bf16x8 oa[4];
      #pragma unroll
      for (int mt = 0; mt < 4; ++mt) {
        int row = mt * 16 + lrow;
        oa[mt] = (row < 49) ? *(const bf16x8*)(qf + swz(row * 192 + ks * 32 + lk8)) : z8;
      }
      #pragma unroll
      for (int nt = 0; nt < 2; ++nt) {
        bf16x8 bfrag = *(const bf16x8*)(WfcTf + ((wave * 2 + nt) * 6 + ks) * 512 + (lane << 3));
        #pragma unroll
        for (int mt = 0; mt < 4; ++mt)
          acc[mt][nt] = __builtin_amdgcn_mfma_f32_16x16x32_bf16(oa[mt], bfrag, acc[mt][nt], 0, 0, 0);
      }
    }

    #pragma unroll
    for (int nt = 0; nt < 2; ++nt) {
      int col = wave * 32 + nt * 16 + lrow;            // 0..191
      float bias = bfc[col];
      #pragma unroll
      for (int mt = 0; mt < 4; ++mt)
        #pragma unroll
        for (int jj = 0; jj < 4; ++jj) {
          int qr = mt * 16 + lg4 + jj;
          if (qr < 49) {
            int t = g * 49 + qr;
            int h = t / 56, w = t - h * 56;
            int hd = h + 3; if (hd >= 56) hd -= 56;    // roll(+3)
            int wd = w + 3; if (wd >= 56) wd -= 56;
            out[(size_t)((b * 56 + hd) * 56 + wd) * 192 + col] = acc[mt][nt][jj] + bias;
          }
        }
    }
  }
}

extern "C" void kernel_launch(void* const* d_in, const int* in_sizes, int n_in,
                              void* d_out, int out_size, void* d_ws, size_t ws_size,
                              hipStream_t stream) {
  const float* x   = (const float*)d_in[0];
  const float* Wq  = (const float*)d_in[1];
  const float* Wk  = (const float*)d_in[2];
  const float* Wv  = (const float*)d_in[3];
  const float* Wfc = (const float*)d_in[4];
  const float* bfc = (const float*)d_in[5];
  const float* pos = (const float*)d_in[6];

  short* WTf   = (short*)d_ws;
  short* WfcTf = (short*)((char*)d_ws + 221184);
  float* biasT = (float*)((char*)d_ws + 294912);

  hipLaunchKernelGGL(prep_kernel, dim3(128), dim3(256), 0, stream,
                     Wq, Wk, Wv, Wfc, pos, WTf, WfcTf, biasT);
  hipLaunchKernelGGL(swin_fused, dim3(2048), dim3(384), 0, stream,
                     x, WTf, WfcTf, biasT, bfc, (float*)d_out);
}

// Round 4
// 215.223 us; speedup vs baseline: 1.6170x; 1.6170x over previous
//
#include <hip/hip_runtime.h>
#include <hip/hip_bf16.h>

typedef __attribute__((ext_vector_type(8))) short bf16x8;
typedef __attribute__((ext_vector_type(4))) short bf16x4;
typedef __attribute__((ext_vector_type(4))) float f32x4;

// ws layout (bytes):
//   WTf  [36 ct][6 ks][64 ln][8] bf16 @ 0       (221184 B)  fragment-major [Wq|Wk|Wv]
//   WfcTf[12 ct][6 ks][64 ln][8] bf16 @ 221184  (73728 B)
//   biasT[3][49 k][49 q] f32        @ 294912    (28812 B)   0=plain 1=+LOWER 2=+RIGHT

__device__ __forceinline__ short f2bf(float f) {
  unsigned u = __float_as_uint(f);
  unsigned r = (u + 0x7FFFu + ((u >> 16) & 1u)) >> 16;
  return (short)(unsigned short)r;
}
// LDS anti-bank-conflict swizzle on flat short index: byte bits[6:4] ^= byte bits[9:7].
// Stays within each 64-short chunk; preserves 8-short (16B) block contiguity.
__device__ __forceinline__ int swz(int f) { return f ^ (((f >> 6) & 7) << 3); }

__global__ void prep_kernel(const float* __restrict__ Wq, const float* __restrict__ Wk,
                            const float* __restrict__ Wv, const float* __restrict__ Wfc,
                            const float* __restrict__ pos,
                            short* __restrict__ WTf, short* __restrict__ WfcTf,
                            float* __restrict__ biasT) {
  int i0 = blockIdx.x * blockDim.x + threadIdx.x;
  int stride = gridDim.x * blockDim.x;
  // WTf fragment-major: lane ln reads 8 bf16 at [ct][ks][ln]: col=ct*16+(ln&15),
  // k = ks*32 + (ln>>4)*8 + e
  for (int o = i0; o < 110592; o += stride) {
    int e = o & 7, ln = (o >> 3) & 63, t = o >> 9;
    int ks = t % 6, ct = t / 6;
    int col = ct * 16 + (ln & 15);
    int k = ks * 32 + ((ln >> 4) << 3) + e;
    const float* W = (col < 192) ? Wq : (col < 384) ? Wk : Wv;
    WTf[o] = f2bf(W[k * 192 + (col % 192)]);
  }
  for (int o = i0; o < 36864; o += stride) {
    int e = o & 7, ln = (o >> 3) & 63, t = o >> 9;
    int ks = t % 6, ct = t / 6;
    int col = ct * 16 + (ln & 15);
    int k = ks * 32 + ((ln >> 4) << 3) + e;
    WfcTf[o] = f2bf(Wfc[k * 192 + col]);
  }
  // transposed bias: biasT[t][k*49 + q] = bias(q,k)  (masks are symmetric in q,k)
  for (int idx = i0; idx < 3 * 2401; idx += stride) {
    int t = idx / 2401, r = idx - t * 2401;
    int kk = r / 49, q = r - kk * 49;
    int ri = kk / 7 - q / 7 + 6;
    int rj = kk % 7 - q % 7 + 6;
    float v = pos[ri * 13 + rj];
    if (t == 1 && ((q >= 28) != (kk >= 28))) v = -1e30f;
    if (t == 2 && ((q % 7 >= 4) != (kk % 7 >= 4))) v = -1e30f;
    biasT[idx] = v;
  }
}

__launch_bounds__(384)
__global__ void swin_fused(const float* __restrict__ x,
                           const short* __restrict__ WTf,
                           const short* __restrict__ WfcTf,
                           const float* __restrict__ biasT,
                           const float* __restrict__ bfc,
                           float* __restrict__ out) {
  // LDS: (9408 + 9408 + 12288) * 2 = 62208 B  -> 2 blocks/CU
  __shared__ short qf[9408];      // q[49][192] flat (swizzled); reused for attn-out
  __shared__ short kf[9408];      // k[49][192] flat (swizzled)
  __shared__ short vT[12288];     // per-window v^T: [6][32 d][64 tok] (swizzled), tok-padded 0

  const int bid = blockIdx.x;
  const int b = bid >> 6;
  const int g = bid & 63;
  const int tid = threadIdx.x;
  const int wave = tid >> 6;
  const int lane = tid & 63;
  const int lrow = lane & 15;            // within-tile row/col
  const int lk8 = (lane >> 4) << 3;      // k-chunk base {0,8,16,24}
  const int lg4 = (lane >> 4) << 2;      // D-frag row base {0,4,8,12}

  const bf16x8 z8 = {0, 0, 0, 0, 0, 0, 0, 0};
  const f32x4 z4 = {0.f, 0.f, 0.f, 0.f};

  for (int i = tid; i < 12288; i += 384) vT[i] = 0;   // zero pad (swizzle-safe: full clear)
  __syncthreads();

  // ---------------- Phase 1: QKV = x_shifted(49 tok) @ [Wq|Wk|Wv]  (M=64pad,N=576,K=192)
  bf16x8 afrag[4][6];
  #pragma unroll
  for (int mt = 0; mt < 4; ++mt) {
    int row = mt * 16 + lrow;
    if (row < 49) {
      int t = g * 49 + row;
      int h = t / 56, w = t - h * 56;
      int hs = h + 3; if (hs >= 56) hs -= 56;        // roll(-3)
      int ws2 = w + 3; if (ws2 >= 56) ws2 -= 56;
      const float* xr = x + ((b * 56 + hs) * 56 + ws2) * 192;
      #pragma unroll
      for (int ks = 0; ks < 6; ++ks) {
        const float* p = xr + 32 * ks + lk8;
        float4 f0 = *(const float4*)(p);
        float4 f1 = *(const float4*)(p + 4);
        bf16x8 a;
        a[0] = f2bf(f0.x); a[1] = f2bf(f0.y); a[2] = f2bf(f0.z); a[3] = f2bf(f0.w);
        a[4] = f2bf(f1.x); a[5] = f2bf(f1.y); a[6] = f2bf(f1.z); a[7] = f2bf(f1.w);
        afrag[mt][ks] = a;
      }
    } else {
      #pragma unroll
      for (int ks = 0; ks < 6; ++ks) afrag[mt][ks] = z8;
    }
  }

  #pragma unroll 1
  for (int nt = 0; nt < 6; ++nt) {
    const short* wr = WTf + ((wave * 6 + nt) * 6) * 512 + (lane << 3);  // coalesced 1KB/wave
    f32x4 acc[4] = {z4, z4, z4, z4};
    #pragma unroll
    for (int ks = 0; ks < 6; ++ks) {
      bf16x8 bfrag = *(const bf16x8*)(wr + ks * 512);
      #pragma unroll
      for (int mt = 0; mt < 4; ++mt)
        acc[mt] = __builtin_amdgcn_mfma_f32_16x16x32_bf16(afrag[mt][ks], bfrag, acc[mt], 0, 0, 0);
    }
    int col = wave * 96 + nt * 16 + lrow;            // 0..575
    #pragma unroll
    for (int mt = 0; mt < 4; ++mt) {
      #pragma unroll
      for (int jj = 0; jj < 4; ++jj) {
        int rowD = mt * 16 + lg4 + jj;
        if (rowD < 49) {
          short v = f2bf(acc[mt][jj]);
          if (col < 192) {
            qf[swz(rowD * 192 + col)] = v;
          } else if (col < 384) {
            kf[swz(rowD * 192 + col - 192)] = v;
          } else {
            int flat = rowD * 192 + col - 384;       // position in [49][192] v-flat
            int win2 = flat / 1568;
            int rem = flat - win2 * 1568;
            vT[swz((win2 * 32 + (rem & 31)) * 64 + (rem >> 5))] = v;
          }
        }
      }
    }
  }
  __syncthreads();

  // ---------------- Phase 2: attention, wave j owns window j. Swapped QK^T:
  // S^T = mfma(K, Q) so lane regs hold P^T in the B-layout of a K=16 MFMA.
  const int j = wave;
  const int qbase = j * 1568;
  {
    bf16x8 ka[4], qb[4];
    #pragma unroll
    for (int t = 0; t < 4; ++t) {
      int row = t * 16 + lrow;
      ka[t] = (row < 49) ? *(const bf16x8*)(kf + swz(qbase + row * 32 + lk8)) : z8;
      qb[t] = (row < 49) ? *(const bf16x8*)(qf + swz(qbase + row * 32 + lk8)) : z8;
    }
    f32x4 st[4][4];   // st[kt][qt]: S^T[k = kt*16+lg4+jj][q = qt*16+lrow]
    #pragma unroll
    for (int kt = 0; kt < 4; ++kt)
      #pragma unroll
      for (int qt = 0; qt < 4; ++qt)
        st[kt][qt] = __builtin_amdgcn_mfma_f32_16x16x32_bf16(ka[kt], qb[qt], z4, 0, 0, 0);

    int win = (g * 6 + j) & 63;
    const float* bt = biasT + ((win >= 56) ? 2401 : (win == 7) ? 4802 : 0);
    #pragma unroll
    for (int kt = 0; kt < 4; ++kt)
      #pragma unroll
      for (int jj = 0; jj < 4; ++jj) {
        int kk = kt * 16 + lg4 + jj;
        #pragma unroll
        for (int qt = 0; qt < 4; ++qt) {
          int qq = qt * 16 + lrow;
          st[kt][qt][jj] = (kk < 49 && qq < 49)
              ? st[kt][qt][jj] * 5.65685424949238f + bt[kk * 49 + qq]   // *sqrt(32)
              : -1e30f;
        }
      }

    // register softmax over k for each q-column, + pack P^T to bf16 B-frags
    bf16x4 pb[4][4];
    #pragma unroll
    for (int qt = 0; qt < 4; ++qt) {
      float m = -1e30f;
      #pragma unroll
      for (int kt = 0; kt < 4; ++kt)
        #pragma unroll
        for (int jj = 0; jj < 4; ++jj)
          m = fmaxf(m, st[kt][qt][jj]);
      m = fmaxf(m, __shfl_xor(m, 16));
      m = fmaxf(m, __shfl_xor(m, 32));
      float sum = 0.f;
      #pragma unroll
      for (int kt = 0; kt < 4; ++kt)
        #pragma unroll
        for (int jj = 0; jj < 4; ++jj) {
          float e = __expf(st[kt][qt][jj] - m);
          st[kt][qt][jj] = e;
          sum += e;
        }
      sum += __shfl_xor(sum, 16);
      sum += __shfl_xor(sum, 32);
      float inv = 1.0f / sum;
      #pragma unroll
      for (int kt = 0; kt < 4; ++kt) {
        bf16x4 p = {f2bf(st[kt][qt][0] * inv), f2bf(st[kt][qt][1] * inv),
                    f2bf(st[kt][qt][2] * inv), f2bf(st[kt][qt][3] * inv)};
        pb[kt][qt] = p;
      }
    }

    // PV: O^T[d][q] = sum_k V^T[d][k] * P^T[k][q], 4 k-tiles of 16
    f32x4 o[2][4] = {{z4, z4, z4, z4}, {z4, z4, z4, z4}};
    #pragma unroll
    for (int dt = 0; dt < 2; ++dt)
      #pragma unroll
      for (int kt = 0; kt < 4; ++kt) {
        bf16x4 va = *(const bf16x4*)(vT + swz((j * 32 + dt * 16 + lrow) * 64 + kt * 16 + lg4));
#if __has_builtin(__builtin_amdgcn_mfma_f32_16x16x16bf16_1k)
        #pragma unroll
        for (int qt = 0; qt < 4; ++qt)
          o[dt][qt] = __builtin_amdgcn_mfma_f32_16x16x16bf16_1k(va, pb[kt][qt], o[dt][qt], 0, 0, 0);
#else
        // padded K=32 fallback: both operands put the 4 real k-values at e=0..3 of each chunk
        bf16x8 va8 = {va[0], va[1], va[2], va[3], 0, 0, 0, 0};
        #pragma unroll
        for (int qt = 0; qt < 4; ++qt) {
          bf16x8 pb8 = {pb[kt][qt][0], pb[kt][qt][1], pb[kt][qt][2], pb[kt][qt][3], 0, 0, 0, 0};
          o[dt][qt] = __builtin_amdgcn_mfma_f32_16x16x32_bf16(va8, pb8, o[dt][qt], 0, 0, 0);
        }
#endif
      }

    // attn-out overwrites q region (same flat positions). Safe: qb consumed via reg deps.
    #pragma unroll
    for (int qt = 0; qt < 4; ++qt) {
      int qq = qt * 16 + lrow;
      if (qq < 49) {
        #pragma unroll
        for (int dt = 0; dt < 2; ++dt)
          #pragma unroll
          for (int jj = 0; jj < 4; ++jj) {
            int d = dt * 16 + lg4 + jj;
            qf[swz(qbase + qq * 32 + d)] = f2bf(o[dt][qt][jj]);
          }
      }
    }
  }
  __syncthreads();

  // ---------------- Phase 3: out = attnout[49][192] @ Wfc + bfc, inverse roll
  {
    f32x4 acc[4][2];
    #pragma unroll
    for (int mt = 0; mt < 4; ++mt)
      #pragma unroll
      for (int nt = 0; nt < 2; ++nt) acc[mt][nt] = z4;

    #pragma unroll
    for (int ks = 0; ks < 6; ++ks) {
      bf16x8 oa[4];
      #pragma unroll
      for (int mt = 0; mt < 4; ++mt) {
        int row = mt * 16 + lrow;
        oa[mt] = (row < 49) ? *(const bf16x8*)(qf + swz(row * 192 + ks * 32 + lk8)) : z8;
      }
      #pragma unroll
      for (int nt = 0; nt < 2; ++nt) {
        bf16x8 bfrag = *(const bf16x8*)(WfcTf + ((wave * 2 + nt) * 6 + ks) * 512 + (lane << 3));
        #pragma unroll
        for (int mt = 0; mt < 4; ++mt)
          acc[mt][nt] = __builtin_amdgcn_mfma_f32_16x16x32_bf16(oa[mt], bfrag, acc[mt][nt], 0, 0, 0);
      }
    }

    #pragma unroll
    for (int nt = 0; nt < 2; ++nt) {
      int col = wave * 32 + nt * 16 + lrow;            // 0..191
      float bias = bfc[col];
      #pragma unroll
      for (int mt = 0; mt < 4; ++mt)
        #pragma unroll
        for (int jj = 0; jj < 4; ++jj) {
          int qr = mt * 16 + lg4 + jj;
          if (qr < 49) {
            int t = g * 49 + qr;
            int h = t / 56, w = t - h * 56;
            int hd = h + 3; if (hd >= 56) hd -= 56;    // roll(+3)
            int wd = w + 3; if (wd >= 56) wd -= 56;
            out[(size_t)((b * 56 + hd) * 56 + wd) * 192 + col] = acc[mt][nt][jj] + bias;
          }
        }
    }
  }
}

extern "C" void kernel_launch(void* const* d_in, const int* in_sizes, int n_in,
                              void* d_out, int out_size, void* d_ws, size_t ws_size,
                              hipStream_t stream) {
  const float* x   = (const float*)d_in[0];
  const float* Wq  = (const float*)d_in[1];
  const float* Wk  = (const float*)d_in[2];
  const float* Wv  = (const float*)d_in[3];
  const float* Wfc = (const float*)d_in[4];
  const float* bfc = (const float*)d_in[5];
  const float* pos = (const float*)d_in[6];

  short* WTf   = (short*)d_ws;
  short* WfcTf = (short*)((char*)d_ws + 221184);
  float* biasT = (float*)((char*)d_ws + 294912);

  hipLaunchKernelGGL(prep_kernel, dim3(128), dim3(256), 0, stream,
                     Wq, Wk, Wv, Wfc, pos, WTf, WfcTf, biasT);
  hipLaunchKernelGGL(swin_fused, dim3(2048), dim3(384), 0, stream,
                     x, WTf, WfcTf, biasT, bfc, (float*)d_out);
}

// Round 5
// 164.526 us; speedup vs baseline: 2.1152x; 1.3081x over previous
//
#include <hip/hip_runtime.h>
#include <hip/hip_bf16.h>

typedef __attribute__((ext_vector_type(8))) short bf16x8;
typedef __attribute__((ext_vector_type(4))) short bf16x4;
typedef __attribute__((ext_vector_type(4))) float f32x4;

// ws layout (bytes):
//   WTf  [36 ct][6 ks][64 ln][8] bf16 @ 0       (221184 B)  fragment-major [Wq|Wk|Wv]
//   WfcTf[12 ct][6 ks][64 ln][8] bf16 @ 221184  (73728 B)
//   biasT[3][49 k][49 q] f32        @ 294912    (28812 B)   0=plain 1=+LOWER 2=+RIGHT

__device__ __forceinline__ short f2bf(float f) {
  __bf16 h = (__bf16)f;                       // native HW convert (cvt_pk-fusable)
  unsigned short u;
  __builtin_memcpy(&u, &h, 2);
  return (short)u;
}
// LDS anti-bank-conflict swizzle on flat short index: byte bits[6:4] ^= byte bits[9:7].
// Stays within each 64-short chunk; preserves 8-short (16B) block contiguity.
__device__ __forceinline__ int swz(int f) { return f ^ (((f >> 6) & 7) << 3); }

__global__ void prep_kernel(const float* __restrict__ Wq, const float* __restrict__ Wk,
                            const float* __restrict__ Wv, const float* __restrict__ Wfc,
                            const float* __restrict__ pos,
                            short* __restrict__ WTf, short* __restrict__ WfcTf,
                            float* __restrict__ biasT) {
  int i0 = blockIdx.x * blockDim.x + threadIdx.x;
  int stride = gridDim.x * blockDim.x;
  // WTf fragment-major: lane ln reads 8 bf16 at [ct][ks][ln]: col=ct*16+(ln&15),
  // k = ks*32 + (ln>>4)*8 + e
  for (int o = i0; o < 110592; o += stride) {
    int e = o & 7, ln = (o >> 3) & 63, t = o >> 9;
    int ks = t % 6, ct = t / 6;
    int col = ct * 16 + (ln & 15);
    int k = ks * 32 + ((ln >> 4) << 3) + e;
    const float* W = (col < 192) ? Wq : (col < 384) ? Wk : Wv;
    WTf[o] = f2bf(W[k * 192 + (col % 192)]);
  }
  for (int o = i0; o < 36864; o += stride) {
    int e = o & 7, ln = (o >> 3) & 63, t = o >> 9;
    int ks = t % 6, ct = t / 6;
    int col = ct * 16 + (ln & 15);
    int k = ks * 32 + ((ln >> 4) << 3) + e;
    WfcTf[o] = f2bf(Wfc[k * 192 + col]);
  }
  // transposed bias: biasT[t][k*49 + q] = bias(q,k)  (masks are symmetric in q,k)
  for (int idx = i0; idx < 3 * 2401; idx += stride) {
    int t = idx / 2401, r = idx - t * 2401;
    int kk = r / 49, q = r - kk * 49;
    int ri = kk / 7 - q / 7 + 6;
    int rj = kk % 7 - q % 7 + 6;
    float v = pos[ri * 13 + rj];
    if (t == 1 && ((q >= 28) != (kk >= 28))) v = -1e30f;
    if (t == 2 && ((q % 7 >= 4) != (kk % 7 >= 4))) v = -1e30f;
    biasT[idx] = v;
  }
}

__launch_bounds__(768)
__global__ void swin_fused(const float* __restrict__ x,
                           const short* __restrict__ WTf,
                           const short* __restrict__ WfcTf,
                           const float* __restrict__ biasT,
                           const float* __restrict__ bfc,
                           float* __restrict__ out) {
  // 12 waves = 2 independent 6-wave sub-groups (one 49-token g-group each).
  // LDS: (18816 + 18816 + 24576) * 2 = 124,416 B  -> forces 12 waves/CU residency.
  __shared__ short qf[18816];     // [2] x q[49][192] flat (swizzled); reused for attn-out
  __shared__ short kf[18816];     // [2] x k[49][192] flat (swizzled)
  __shared__ short vT[24576];     // [2] x per-window v^T [6][32 d][64 tok] (swizzled), pad 0

  const int bid = blockIdx.x;
  const int tid = threadIdx.x;
  const int wave = tid >> 6;
  const int lane = tid & 63;
  const int sub = (wave >= 6) ? 1 : 0;   // which g-group this wave serves
  const int wl = wave - sub * 6;         // wave index within sub-group [0,6)
  const int gg = bid * 2 + sub;          // global group id [0,2048)
  const int b = gg >> 6;                 // batch
  const int gl = gg & 63;                // group within batch
  const int lrow = lane & 15;            // within-tile row/col
  const int lk8 = (lane >> 4) << 3;      // k-chunk base {0,8,16,24}
  const int lg4 = (lane >> 4) << 2;      // D-frag row base {0,4,8,12}
  const int qoff = sub * 9408;
  const int voff = sub * 12288;

  const bf16x8 z8 = {0, 0, 0, 0, 0, 0, 0, 0};
  const f32x4 z4 = {0.f, 0.f, 0.f, 0.f};

  // ---------------- Phase 1 A-fragments: x loads issue first (hidden under zeroing)
  bf16x8 afrag[4][6];
  #pragma unroll
  for (int mt = 0; mt < 4; ++mt) {
    int row = mt * 16 + lrow;
    if (row < 49) {
      int t = gl * 49 + row;
      int h = t / 56, w = t - h * 56;
      int hs = h + 3; if (hs >= 56) hs -= 56;        // roll(-3)
      int ws2 = w + 3; if (ws2 >= 56) ws2 -= 56;
      const float* xr = x + ((b * 56 + hs) * 56 + ws2) * 192;
      #pragma unroll
      for (int ks = 0; ks < 6; ++ks) {
        const float* p = xr + 32 * ks + lk8;
        float4 f0 = *(const float4*)(p);
        float4 f1 = *(const float4*)(p + 4);
        bf16x8 a;
        a[0] = f2bf(f0.x); a[1] = f2bf(f0.y); a[2] = f2bf(f0.z); a[3] = f2bf(f0.w);
        a[4] = f2bf(f1.x); a[5] = f2bf(f1.y); a[6] = f2bf(f1.z); a[7] = f2bf(f1.w);
        afrag[mt][ks] = a;
      }
    } else {
      #pragma unroll
      for (int ks = 0; ks < 6; ++ks) afrag[mt][ks] = z8;
    }
  }

  for (int i = tid; i < 24576; i += 768) vT[i] = 0;   // zero v^T pad (full clear)
  __syncthreads();

  // ---------------- Phase 1: QKV = x_shifted(49 tok) @ [Wq|Wk|Wv]  (M=64pad,N=576,K=192)
  #pragma unroll 1
  for (int nt = 0; nt < 6; ++nt) {
    const short* wr = WTf + ((wl * 6 + nt) * 6) * 512 + (lane << 3);  // coalesced 1KB/wave
    f32x4 acc[4] = {z4, z4, z4, z4};
    __builtin_amdgcn_s_setprio(1);
    #pragma unroll
    for (int ks = 0; ks < 6; ++ks) {
      bf16x8 bfrag = *(const bf16x8*)(wr + ks * 512);
      #pragma unroll
      for (int mt = 0; mt < 4; ++mt)
        acc[mt] = __builtin_amdgcn_mfma_f32_16x16x32_bf16(afrag[mt][ks], bfrag, acc[mt], 0, 0, 0);
    }
    __builtin_amdgcn_s_setprio(0);
    int col = wl * 96 + nt * 16 + lrow;              // 0..575
    #pragma unroll
    for (int mt = 0; mt < 4; ++mt) {
      #pragma unroll
      for (int jj = 0; jj < 4; ++jj) {
        int rowD = mt * 16 + lg4 + jj;
        if (rowD < 49) {
          short v = f2bf(acc[mt][jj]);
          if (col < 192) {
            qf[qoff + swz(rowD * 192 + col)] = v;
          } else if (col < 384) {
            kf[qoff + swz(rowD * 192 + col - 192)] = v;
          } else {
            int flat = rowD * 192 + col - 384;       // position in [49][192] v-flat
            int win2 = flat / 1568;
            int rem = flat - win2 * 1568;
            vT[voff + swz((win2 * 32 + (rem & 31)) * 64 + (rem >> 5))] = v;
          }
        }
      }
    }
  }
  __syncthreads();

  // ---------------- Phase 2: attention, wave wl owns window wl of its sub-group.
  // Swapped QK^T: S^T = mfma(K, Q) so lane regs hold P^T in B-layout of a K=16 MFMA.
  const int j = wl;
  const int qbase = j * 1568;
  {
    bf16x8 ka[4], qb[4];
    #pragma unroll
    for (int t = 0; t < 4; ++t) {
      int row = t * 16 + lrow;
      ka[t] = (row < 49) ? *(const bf16x8*)(kf + qoff + swz(qbase + row * 32 + lk8)) : z8;
      qb[t] = (row < 49) ? *(const bf16x8*)(qf + qoff + swz(qbase + row * 32 + lk8)) : z8;
    }
    f32x4 st[4][4];   // st[kt][qt]: S^T[k = kt*16+lg4+jj][q = qt*16+lrow]
    __builtin_amdgcn_s_setprio(1);
    #pragma unroll
    for (int kt = 0; kt < 4; ++kt)
      #pragma unroll
      for (int qt = 0; qt < 4; ++qt)
        st[kt][qt] = __builtin_amdgcn_mfma_f32_16x16x32_bf16(ka[kt], qb[qt], z4, 0, 0, 0);
    __builtin_amdgcn_s_setprio(0);

    int win = (gl * 6 + j) & 63;
    const float* bt = biasT + ((win >= 56) ? 2401 : (win == 7) ? 4802 : 0);
    #pragma unroll
    for (int kt = 0; kt < 4; ++kt)
      #pragma unroll
      for (int jj = 0; jj < 4; ++jj) {
        int kk = kt * 16 + lg4 + jj;
        #pragma unroll
        for (int qt = 0; qt < 4; ++qt) {
          int qq = qt * 16 + lrow;
          st[kt][qt][jj] = (kk < 49 && qq < 49)
              ? st[kt][qt][jj] * 5.65685424949238f + bt[kk * 49 + qq]   // *sqrt(32)
              : -1e30f;
        }
      }

    // register softmax over k for each q-column, + pack P^T to bf16 B-frags
    bf16x4 pb[4][4];
    #pragma unroll
    for (int qt = 0; qt < 4; ++qt) {
      float m = -1e30f;
      #pragma unroll
      for (int kt = 0; kt < 4; ++kt)
        #pragma unroll
        for (int jj = 0; jj < 4; ++jj)
          m = fmaxf(m, st[kt][qt][jj]);
      m = fmaxf(m, __shfl_xor(m, 16));
      m = fmaxf(m, __shfl_xor(m, 32));
      float sum = 0.f;
      #pragma unroll
      for (int kt = 0; kt < 4; ++kt)
        #pragma unroll
        for (int jj = 0; jj < 4; ++jj) {
          float e = __expf(st[kt][qt][jj] - m);
          st[kt][qt][jj] = e;
          sum += e;
        }
      sum += __shfl_xor(sum, 16);
      sum += __shfl_xor(sum, 32);
      float inv = 1.0f / sum;
      #pragma unroll
      for (int kt = 0; kt < 4; ++kt) {
        bf16x4 p = {f2bf(st[kt][qt][0] * inv), f2bf(st[kt][qt][1] * inv),
                    f2bf(st[kt][qt][2] * inv), f2bf(st[kt][qt][3] * inv)};
        pb[kt][qt] = p;
      }
    }

    // PV: O^T[d][q] = sum_k V^T[d][k] * P^T[k][q], 4 k-tiles of 16
    f32x4 o[2][4] = {{z4, z4, z4, z4}, {z4, z4, z4, z4}};
    #pragma unroll
    for (int dt = 0; dt < 2; ++dt)
      #pragma unroll
      for (int kt = 0; kt < 4; ++kt) {
        bf16x4 va = *(const bf16x4*)(vT + voff + swz((j * 32 + dt * 16 + lrow) * 64 + kt * 16 + lg4));
#if __has_builtin(__builtin_amdgcn_mfma_f32_16x16x16bf16_1k)
        #pragma unroll
        for (int qt = 0; qt < 4; ++qt)
          o[dt][qt] = __builtin_amdgcn_mfma_f32_16x16x16bf16_1k(va, pb[kt][qt], o[dt][qt], 0, 0, 0);
#else
        // padded K=32 fallback: both operands put the 4 real k-values at e=0..3 of each chunk
        bf16x8 va8 = {va[0], va[1], va[2], va[3], 0, 0, 0, 0};
        #pragma unroll
        for (int qt = 0; qt < 4; ++qt) {
          bf16x8 pb8 = {pb[kt][qt][0], pb[kt][qt][1], pb[kt][qt][2], pb[kt][qt][3], 0, 0, 0, 0};
          o[dt][qt] = __builtin_amdgcn_mfma_f32_16x16x32_bf16(va8, pb8, o[dt][qt], 0, 0, 0);
        }
#endif
      }

    // attn-out overwrites q region (same flat positions). Safe: qb consumed via reg deps.
    #pragma unroll
    for (int qt = 0; qt < 4; ++qt) {
      int qq = qt * 16 + lrow;
      if (qq < 49) {
        #pragma unroll
        for (int dt = 0; dt < 2; ++dt)
          #pragma unroll
          for (int jj = 0; jj < 4; ++jj) {
            int d = dt * 16 + lg4 + jj;
            qf[qoff + swz(qbase + qq * 32 + d)] = f2bf(o[dt][qt][jj]);
          }
      }
    }
  }
  __syncthreads();

  // ---------------- Phase 3: out = attnout[49][192] @ Wfc + bfc, inverse roll
  {
    f32x4 acc[4][2];
    #pragma unroll
    for (int mt = 0; mt < 4; ++mt)
      #pragma unroll
      for (int nt = 0; nt < 2; ++nt) acc[mt][nt] = z4;

    #pragma unroll
    for (int ks = 0; ks < 6; ++ks) {
      bf16x8 oa[4];
      #pragma unroll
      for (int mt = 0; mt < 4; ++mt) {
        int row = mt * 16 + lrow;
        oa[mt] = (row < 49) ? *(const bf16x8*)(qf + qoff + swz(row * 192 + ks * 32 + lk8)) : z8;
      }
      #pragma unroll
      for (int nt = 0; nt < 2; ++nt) {
        bf16x8 bfrag = *(const bf16x8*)(WfcTf + ((wl * 2 + nt) * 6 + ks) * 512 + (lane << 3));
        #pragma unroll
        for (int mt = 0; mt < 4; ++mt)
          acc[mt][nt] = __builtin_amdgcn_mfma_f32_16x16x32_bf16(oa[mt], bfrag, acc[mt][nt], 0, 0, 0);
      }
    }

    // hoisted addressing: one rolled row pointer per (mt,jj), two stores each
    const int col0 = wl * 32 + lrow;                 // 0..191 (nt=0); nt=1 -> +16
    float bias0 = bfc[col0];
    float bias1 = bfc[col0 + 16];
    #pragma unroll
    for (int mt = 0; mt < 4; ++mt)
      #pragma unroll
      for (int jj = 0; jj < 4; ++jj) {
        int qr = mt * 16 + lg4 + jj;
        if (qr < 49) {
          int t = gl * 49 + qr;
          int h = t / 56, w = t - h * 56;
          int hd = h + 3; if (hd >= 56) hd -= 56;    // roll(+3)
          int wd = w + 3; if (wd >= 56) wd -= 56;
          float* orow = out + (size_t)((b * 56 + hd) * 56 + wd) * 192;
          orow[col0]      = acc[mt][0][jj] + bias0;
          orow[col0 + 16] = acc[mt][1][jj] + bias1;
        }
      }
  }
}

extern "C" void kernel_launch(void* const* d_in, const int* in_sizes, int n_in,
                              void* d_out, int out_size, void* d_ws, size_t ws_size,
                              hipStream_t stream) {
  const float* x   = (const float*)d_in[0];
  const float* Wq  = (const float*)d_in[1];
  const float* Wk  = (const float*)d_in[2];
  const float* Wv  = (const float*)d_in[3];
  const float* Wfc = (const float*)d_in[4];
  const float* bfc = (const float*)d_in[5];
  const float* pos = (const float*)d_in[6];

  short* WTf   = (short*)d_ws;
  short* WfcTf = (short*)((char*)d_ws + 221184);
  float* biasT = (float*)((char*)d_ws + 294912);

  hipLaunchKernelGGL(prep_kernel, dim3(128), dim3(256), 0, stream,
                     Wq, Wk, Wv, Wfc, pos, WTf, WfcTf, biasT);
  hipLaunchKernelGGL(swin_fused, dim3(1024), dim3(768), 0, stream,
                     x, WTf, WfcTf, biasT, bfc, (float*)d_out);
}

// Round 6
// 148.034 us; speedup vs baseline: 2.3509x; 1.1114x over previous
//
#include <hip/hip_runtime.h>
#include <hip/hip_bf16.h>

typedef __attribute__((ext_vector_type(8))) short bf16x8;
typedef __attribute__((ext_vector_type(4))) short bf16x4;
typedef __attribute__((ext_vector_type(4))) float f32x4;

// ws layout (bytes):
//   WTf  [36 ct][6 ks][64 ln][8] bf16 @ 0       (221184 B)  fragment-major [Wq|Wk|Wv]
//   WfcTf[12 ct][6 ks][64 ln][8] bf16 @ 221184  (73728 B)
//   biasT[3][49 k][49 q] f32        @ 294912    (28812 B)   0=plain 1=+LOWER 2=+RIGHT

__device__ __forceinline__ short f2bf(float f) {
  __bf16 h = (__bf16)f;                       // native HW convert
  unsigned short u;
  __builtin_memcpy(&u, &h, 2);
  return (short)u;
}
// LDS anti-bank-conflict swizzle on flat short index: byte bits[6:4] ^= byte bits[9:7].
// Stays within each 64-short chunk; preserves 8-short (16B) and 4-short (8B) alignment.
__device__ __forceinline__ int swz(int f) { return f ^ (((f >> 6) & 7) << 3); }

__global__ void prep_kernel(const float* __restrict__ Wq, const float* __restrict__ Wk,
                            const float* __restrict__ Wv, const float* __restrict__ Wfc,
                            const float* __restrict__ pos,
                            short* __restrict__ WTf, short* __restrict__ WfcTf,
                            float* __restrict__ biasT) {
  int i0 = blockIdx.x * blockDim.x + threadIdx.x;
  int stride = gridDim.x * blockDim.x;
  // WTf fragment-major: lane ln reads 8 bf16 at [ct][ks][ln]: col=ct*16+(ln&15),
  // k = ks*32 + (ln>>4)*8 + e
  for (int o = i0; o < 110592; o += stride) {
    int e = o & 7, ln = (o >> 3) & 63, t = o >> 9;
    int ks = t % 6, ct = t / 6;
    int col = ct * 16 + (ln & 15);
    int k = ks * 32 + ((ln >> 4) << 3) + e;
    const float* W = (col < 192) ? Wq : (col < 384) ? Wk : Wv;
    WTf[o] = f2bf(W[k * 192 + (col % 192)]);
  }
  for (int o = i0; o < 36864; o += stride) {
    int e = o & 7, ln = (o >> 3) & 63, t = o >> 9;
    int ks = t % 6, ct = t / 6;
    int col = ct * 16 + (ln & 15);
    int k = ks * 32 + ((ln >> 4) << 3) + e;
    WfcTf[o] = f2bf(Wfc[k * 192 + col]);
  }
  // transposed bias: biasT[t][k*49 + q] = bias(q,k)  (masks are symmetric in q,k)
  for (int idx = i0; idx < 3 * 2401; idx += stride) {
    int t = idx / 2401, r = idx - t * 2401;
    int kk = r / 49, q = r - kk * 49;
    int ri = kk / 7 - q / 7 + 6;
    int rj = kk % 7 - q % 7 + 6;
    float v = pos[ri * 13 + rj];
    if (t == 1 && ((q >= 28) != (kk >= 28))) v = -1e30f;
    if (t == 2 && ((q % 7 >= 4) != (kk % 7 >= 4))) v = -1e30f;
    biasT[idx] = v;
  }
}

__launch_bounds__(768)
__global__ void swin_fused(const float* __restrict__ x,
                           const short* __restrict__ WTf,
                           const short* __restrict__ WfcTf,
                           const float* __restrict__ biasT,
                           const float* __restrict__ bfc,
                           float* __restrict__ out) {
  // 12 waves = 2 independent 6-wave sub-groups (one 49-token g-group each).
  // LDS: (18816 + 18816 + 24576) * 2 = 124,416 B -> forces 12 waves/CU residency.
  // 768-thread block caps VGPR at ~84; kernel is restructured to FIT (no spills).
  __shared__ short qf[18816];     // [2] x q[49][192] flat (swizzled); reused for attn-out
  __shared__ short kf[18816];     // [2] x k[49][192] flat (swizzled)
  __shared__ short vT[24576];     // [2] x per-window v^T [6][32 d][64 tok] (swizzled)

  const int bid = blockIdx.x;
  const int tid = threadIdx.x;
  const int wave = tid >> 6;
  const int lane = tid & 63;
  const int sub = (wave >= 6) ? 1 : 0;   // which g-group this wave serves
  const int wl = wave - sub * 6;         // wave index within sub-group [0,6)
  const int gg = bid * 2 + sub;          // global group id [0,2048)
  const int b = gg >> 6;                 // batch
  const int gl = gg & 63;                // group within batch
  const int lrow = lane & 15;            // within-tile row/col
  const int lk8 = (lane >> 4) << 3;      // k-chunk base {0,8,16,24}
  const int lg4 = (lane >> 4) << 2;      // D-frag row base {0,4,8,12}
  const int qoff = sub * 9408;
  const int voff = sub * 12288;

  const bf16x8 z8 = {0, 0, 0, 0, 0, 0, 0, 0};
  const f32x4 z4 = {0.f, 0.f, 0.f, 0.f};

  // zero only the v^T token-pad (tok 49..63); disjoint from live v writes, so no
  // barrier needed here — the post-phase-1 barrier covers visibility for phase 2.
  for (int i = tid; i < 2 * 2880; i += 768) {
    int s = (i >= 2880) ? 1 : 0;
    int r = i - s * 2880;
    int wd = r / 15, tok = 49 + (r - wd * 15);
    vT[s * 12288 + swz(wd * 64 + tok)] = 0;
  }

  // ---------------- Phase 1: QKV = x_shifted(49 tok) @ [Wq|Wk|Wv]  (M=64pad,N=576,K=192)
  // Two m-halves (rows 0..31, 32..48): afrag[2][6] = 48 VGPRs, each half loads its
  // OWN x rows (no duplicate traffic). Tile remap: each wave owns 2 q + 2 k + 2 v tiles.
  #pragma unroll 1
  for (int half = 0; half < 2; ++half) {
    bf16x8 afrag[2][6];
    #pragma unroll
    for (int mh = 0; mh < 2; ++mh) {
      int row = (half * 2 + mh) * 16 + lrow;
      if (row < 49) {
        int t = gl * 49 + row;
        int h = t / 56, w = t - h * 56;
        int hs = h + 3; if (hs >= 56) hs -= 56;        // roll(-3)
        int ws2 = w + 3; if (ws2 >= 56) ws2 -= 56;
        const float* xr = x + ((b * 56 + hs) * 56 + ws2) * 192 + lk8;
        #pragma unroll
        for (int ks = 0; ks < 6; ++ks) {
          float4 f0 = *(const float4*)(xr + 32 * ks);
          float4 f1 = *(const float4*)(xr + 32 * ks + 4);
          bf16x8 a;
          a[0] = f2bf(f0.x); a[1] = f2bf(f0.y); a[2] = f2bf(f0.z); a[3] = f2bf(f0.w);
          a[4] = f2bf(f1.x); a[5] = f2bf(f1.y); a[6] = f2bf(f1.z); a[7] = f2bf(f1.w);
          afrag[mh][ks] = a;
        }
      } else {
        #pragma unroll
        for (int ks = 0; ks < 6; ++ks) afrag[mh][ks] = z8;
      }
    }
    #pragma unroll 1
    for (int nt = 0; nt < 6; ++nt) {
      // column-tile remap: nt 0,1 -> q; 2,3 -> k; 4,5 -> v (each wave 2 of each)
      int ct = (nt < 2) ? (wl * 2 + nt)
             : (nt < 4) ? (12 + wl * 2 + (nt - 2))
                        : (24 + wl * 2 + (nt - 4));
      const short* wr = WTf + ct * 3072 + (lane << 3);   // coalesced 1KB/wave
      f32x4 acc0 = z4, acc1 = z4;
      __builtin_amdgcn_s_setprio(1);
      #pragma unroll
      for (int ks = 0; ks < 6; ++ks) {
        bf16x8 bfrag = *(const bf16x8*)(wr + ks * 512);
        acc0 = __builtin_amdgcn_mfma_f32_16x16x32_bf16(afrag[0][ks], bfrag, acc0, 0, 0, 0);
        acc1 = __builtin_amdgcn_mfma_f32_16x16x32_bf16(afrag[1][ks], bfrag, acc1, 0, 0, 0);
      }
      __builtin_amdgcn_s_setprio(0);
      int colb = wl * 32 + (nt & 1) * 16 + lrow;   // col within its 192-col section
      #pragma unroll
      for (int mh = 0; mh < 2; ++mh) {
        f32x4 a4 = mh ? acc1 : acc0;
        #pragma unroll
        for (int jj = 0; jj < 4; ++jj) {
          int rowD = (half * 2 + mh) * 16 + lg4 + jj;
          if (rowD < 49) {
            short v = f2bf(a4[jj]);
            if (nt < 2) {
              qf[qoff + swz(rowD * 192 + colb)] = v;
            } else if (nt < 4) {
              kf[qoff + swz(rowD * 192 + colb)] = v;
            } else {
              int flat = rowD * 192 + colb;        // position in [49][192] v-flat
              int w2 = flat / 1568;
              int rem = flat - w2 * 1568;
              vT[voff + swz((w2 * 32 + (rem & 31)) * 64 + (rem >> 5))] = v;
            }
          }
        }
      }
    }
  }
  __syncthreads();

  // ---------------- Phase 2: attention, wave wl owns window wl of its sub-group.
  // Swapped QK^T: S^T = mfma(K, Q); streaming per-qt softmax + immediate PV + writeback
  // keeps peak live regs ~70 (va 16 + ka 16 + st 16 + pb 8 + transients).
  const int j = wl;
  const int qbase = j * 1568;
  {
    int win = (gl * 6 + j) & 63;
    const float* bt = biasT + ((win >= 56) ? 2401 : (win == 7) ? 4802 : 0);

    bf16x4 va[2][4];
    #pragma unroll
    for (int dt = 0; dt < 2; ++dt)
      #pragma unroll
      for (int kt = 0; kt < 4; ++kt)
        va[dt][kt] = *(const bf16x4*)(vT + voff + swz((j * 32 + dt * 16 + lrow) * 64 + kt * 16 + lg4));

    bf16x8 ka[4];
    #pragma unroll
    for (int kt = 0; kt < 4; ++kt) {
      int row = kt * 16 + lrow;
      ka[kt] = (row < 49) ? *(const bf16x8*)(kf + qoff + swz(qbase + row * 32 + lk8)) : z8;
    }

    #pragma unroll
    for (int qt = 0; qt < 4; ++qt) {
      int qq = qt * 16 + lrow;
      bf16x8 qb = (qq < 49) ? *(const bf16x8*)(qf + qoff + swz(qbase + qq * 32 + lk8)) : z8;
      f32x4 st[4];
      __builtin_amdgcn_s_setprio(1);
      #pragma unroll
      for (int kt = 0; kt < 4; ++kt)
        st[kt] = __builtin_amdgcn_mfma_f32_16x16x32_bf16(ka[kt], qb, z4, 0, 0, 0);
      __builtin_amdgcn_s_setprio(0);

      #pragma unroll
      for (int kt = 0; kt < 4; ++kt)
        #pragma unroll
        for (int jj = 0; jj < 4; ++jj) {
          int kk = kt * 16 + lg4 + jj;
          st[kt][jj] = (kk < 49 && qq < 49)
              ? st[kt][jj] * 5.65685424949238f + bt[kk * 49 + qq]   // *sqrt(32)
              : -1e30f;
        }

      float m = -1e30f;
      #pragma unroll
      for (int kt = 0; kt < 4; ++kt)
        #pragma unroll
        for (int jj = 0; jj < 4; ++jj) m = fmaxf(m, st[kt][jj]);
      m = fmaxf(m, __shfl_xor(m, 16));
      m = fmaxf(m, __shfl_xor(m, 32));
      float sum = 0.f;
      #pragma unroll
      for (int kt = 0; kt < 4; ++kt)
        #pragma unroll
        for (int jj = 0; jj < 4; ++jj) {
          float e = __expf(st[kt][jj] - m);
          st[kt][jj] = e;
          sum += e;
        }
      sum += __shfl_xor(sum, 16);
      sum += __shfl_xor(sum, 32);
      float inv = 1.0f / sum;
      bf16x4 pb[4];
      #pragma unroll
      for (int kt = 0; kt < 4; ++kt) {
        bf16x4 p = {f2bf(st[kt][0] * inv), f2bf(st[kt][1] * inv),
                    f2bf(st[kt][2] * inv), f2bf(st[kt][3] * inv)};
        pb[kt] = p;
      }

      // PV for this qt, immediate writeback (frees o regs). Safe vs later qb reads:
      // row sets are partitioned by qt; same-wave DS ops execute in issue order.
      #pragma unroll
      for (int dt = 0; dt < 2; ++dt) {
        f32x4 oo = z4;
#if __has_builtin(__builtin_amdgcn_mfma_f32_16x16x16bf16_1k)
        #pragma unroll
        for (int kt = 0; kt < 4; ++kt)
          oo = __builtin_amdgcn_mfma_f32_16x16x16bf16_1k(va[dt][kt], pb[kt], oo, 0, 0, 0);
#else
        #pragma unroll
        for (int kt = 0; kt < 4; ++kt) {
          bf16x8 va8 = {va[dt][kt][0], va[dt][kt][1], va[dt][kt][2], va[dt][kt][3], 0, 0, 0, 0};
          bf16x8 pb8 = {pb[kt][0], pb[kt][1], pb[kt][2], pb[kt][3], 0, 0, 0, 0};
          oo = __builtin_amdgcn_mfma_f32_16x16x32_bf16(va8, pb8, oo, 0, 0, 0);
        }
#endif
        if (qq < 49) {
          bf16x4 ov = {f2bf(oo[0]), f2bf(oo[1]), f2bf(oo[2]), f2bf(oo[3])};
          *(bf16x4*)(qf + qoff + swz(qbase + qq * 32 + dt * 16 + lg4)) = ov;
        }
      }
    }
  }
  __syncthreads();

  // ---------------- Phase 3: out = attnout[49][192] @ Wfc + bfc, inverse roll
  {
    f32x4 acc[4][2];
    #pragma unroll
    for (int mt = 0; mt < 4; ++mt)
      #pragma unroll
      for (int nt = 0; nt < 2; ++nt) acc[mt][nt] = z4;

    #pragma unroll
    for (int ks = 0; ks < 6; ++ks) {
      bf16x8 oa[4];
      #pragma unroll
      for (int mt = 0; mt < 4; ++mt) {
        int row = mt * 16 + lrow;
        oa[mt] = (row < 49) ? *(const bf16x8*)(qf + qoff + swz(row * 192 + ks * 32 + lk8)) : z8;
      }
      #pragma unroll
      for (int nt = 0; nt < 2; ++nt) {
        bf16x8 bfrag = *(const bf16x8*)(WfcTf + ((wl * 2 + nt) * 6 + ks) * 512 + (lane << 3));
        #pragma unroll
        for (int mt = 0; mt < 4; ++mt)
          acc[mt][nt] = __builtin_amdgcn_mfma_f32_16x16x32_bf16(oa[mt], bfrag, acc[mt][nt], 0, 0, 0);
      }
    }

    // hoisted addressing: one rolled row pointer per (mt,jj), two stores each
    const int col0 = wl * 32 + lrow;                 // 0..191 (nt=0); nt=1 -> +16
    float bias0 = bfc[col0];
    float bias1 = bfc[col0 + 16];
    #pragma unroll
    for (int mt = 0; mt < 4; ++mt)
      #pragma unroll
      for (int jj = 0; jj < 4; ++jj) {
        int qr = mt * 16 + lg4 + jj;
        if (qr < 49) {
          int t = gl * 49 + qr;
          int h = t / 56, w = t - h * 56;
          int hd = h + 3; if (hd >= 56) hd -= 56;    // roll(+3)
          int wd = w + 3; if (wd >= 56) wd -= 56;
          float* orow = out + (size_t)((b * 56 + hd) * 56 + wd) * 192;
          orow[col0]      = acc[mt][0][jj] + bias0;
          orow[col0 + 16] = acc[mt][1][jj] + bias1;
        }
      }
  }
}

extern "C" void kernel_launch(void* const* d_in, const int* in_sizes, int n_in,
                              void* d_out, int out_size, void* d_ws, size_t ws_size,
                              hipStream_t stream) {
  const float* x   = (const float*)d_in[0];
  const float* Wq  = (const float*)d_in[1];
  const float* Wk  = (const float*)d_in[2];
  const float* Wv  = (const float*)d_in[3];
  const float* Wfc = (const float*)d_in[4];
  const float* bfc = (const float*)d_in[5];
  const float* pos = (const float*)d_in[6];

  short* WTf   = (short*)d_ws;
  short* WfcTf = (short*)((char*)d_ws + 221184);
  float* biasT = (float*)((char*)d_ws + 294912);

  hipLaunchKernelGGL(prep_kernel, dim3(128), dim3(256), 0, stream,
                     Wq, Wk, Wv, Wfc, pos, WTf, WfcTf, biasT);
  hipLaunchKernelGGL(swin_fused, dim3(1024), dim3(768), 0, stream,
                     x, WTf, WfcTf, biasT, bfc, (float*)d_out);
}